// Round 12
// baseline (258.608 us; speedup 1.0000x reference)
//
#include <hip/hip_runtime.h>
#include <hip/hip_bf16.h>

typedef __attribute__((ext_vector_type(8))) short bf16x8;
typedef __attribute__((ext_vector_type(4))) float f32x4;
typedef unsigned short u16;
typedef unsigned int u32;

#define B_ 2
#define S_ 2048
#define E_ 2048
#define H_ 16
#define DK_ 128
#define SCALE_ 0.08838834764831845f  // 1/sqrt(128)
#define THR_RAW_ 90.5f               // defer-max threshold: 8 / SCALE_
#define PPAD_ 76                     // P row stride: 38 dwords -> conflict-free P writes

#define MFMA16(a,b,c) __builtin_amdgcn_mfma_f32_16x16x32_bf16((a),(b),(c),0,0,0)
#define GLD16(g, l) __builtin_amdgcn_global_load_lds((const __attribute__((address_space(1))) void*)(g), (__attribute__((address_space(3))) void*)(l), 16, 0, 0)

__device__ __forceinline__ float b2f(short s) {
    u32 u = ((u32)(u16)s) << 16;
    float f; __builtin_memcpy(&f, &u, 4); return f;
}

// ---------------- casts: one launch, gridy 0..4 selects tensor ----------------
__global__ void cast_all(const float* __restrict__ x,
                         const float* __restrict__ w0, const float* __restrict__ w1,
                         const float* __restrict__ w2, const float* __restrict__ w3,
                         __hip_bfloat16* __restrict__ xo,
                         __hip_bfloat16* __restrict__ o0, __hip_bfloat16* __restrict__ o1,
                         __hip_bfloat16* __restrict__ o2, __hip_bfloat16* __restrict__ o3,
                         int nx4, int nw4) {
    int i = blockIdx.x * blockDim.x + threadIdx.x;
    const int y = blockIdx.y;
    const float* in; __hip_bfloat16* out; int n4;
    if (y == 0)      { in = x;  out = xo; n4 = nx4; }
    else if (y == 1) { in = w0; out = o0; n4 = nw4; }
    else if (y == 2) { in = w1; out = o1; n4 = nw4; }
    else if (y == 3) { in = w2; out = o2; n4 = nw4; }
    else             { in = w3; out = o3; n4 = nw4; }
    if (i >= n4) return;
    float4 v = ((const float4*)in)[i];
    __hip_bfloat16 ob[4] = {__float2bfloat16(v.x), __float2bfloat16(v.y),
                            __float2bfloat16(v.z), __float2bfloat16(v.w)};
    ushort4 u; __builtin_memcpy(&u, ob, 8);
    ((ushort4*)out)[i] = u;
}

// ---------------- trig table ----------------
__global__ void trig_table(const float* __restrict__ pe, float* __restrict__ ct,
                           float* __restrict__ st) {
    int t = blockIdx.x * blockDim.x + threadIdx.x;
    int s = t >> 6, d2 = t & 63;
    float ang = pe[(size_t)s * DK_ + 2 * d2];
    ct[t] = cosf(ang);
    st[t] = sinf(ang);
}

// ---------------- fused QKV projection GEMM + RoPE epilogue (round-3 exact, NO setprio) --
// grid (32, 48): which = blockIdx.y/16 selects {wq,wk,wv}; ntile = blockIdx.y%16.
// Dispatch order x-fast keeps the X working set per XCD small (FETCH ~120MB, 107us).
// setprio removed: m190 — null/negative on barrier-lockstep GEMM, and it cost 8 VGPR.
__global__ __launch_bounds__(256, 2)
void gemm_qkv(const __hip_bfloat16* __restrict__ X,
              const __hip_bfloat16* __restrict__ WQ, const __hip_bfloat16* __restrict__ WK,
              const __hip_bfloat16* __restrict__ WV,
              __hip_bfloat16* __restrict__ Qo, __hip_bfloat16* __restrict__ Ko,
              __hip_bfloat16* __restrict__ Vo,
              const float* __restrict__ CT, const float* __restrict__ ST)
{
    __shared__ __align__(16) __hip_bfloat16 As[128 * 64];
    __shared__ __align__(16) __hip_bfloat16 Bs[128 * 64];
    const int tid = threadIdx.x;
    const int lane = tid & 63, wv = tid >> 6;
    const int wr = wv >> 1, wc = wv & 1;
    const int which = blockIdx.y >> 4;
    const __hip_bfloat16* W = which == 0 ? WQ : which == 1 ? WK : WV;
    const int m0 = blockIdx.x * 128, n0 = (blockIdx.y & 15) * 128;
    const int g = lane >> 4, c = lane & 15;
    const int K = E_;

    f32x4 acc[4][4];
    #pragma unroll
    for (int i = 0; i < 4; ++i)
        #pragma unroll
        for (int j = 0; j < 4; ++j) acc[i][j] = f32x4{0.f, 0.f, 0.f, 0.f};

    for (int k0 = 0; k0 < K; k0 += 64) {
        __syncthreads();
        #pragma unroll
        for (int it = 0; it < 4; ++it) {
            int o = (it * 256 + tid) * 16;
            int row = o >> 7;
            int colb = (o ^ ((row & 7) << 4)) & 127;
            GLD16((const char*)(X + (size_t)(m0 + row) * K + k0) + colb, (char*)As + o);
            GLD16((const char*)(W + (size_t)(n0 + row) * K + k0) + colb, (char*)Bs + o);
        }
        __syncthreads();
        #pragma unroll
        for (int ks = 0; ks < 2; ++ks) {
            bf16x8 af[4], bfm[4];
            #pragma unroll
            for (int i = 0; i < 4; ++i) {
                int arow = wr * 64 + i * 16 + c;
                int ab = arow * 128 + ((ks * 64 + g * 16) ^ ((arow & 7) << 4));
                af[i] = *(const bf16x8*)((const char*)As + ab);
                int brow = wc * 64 + i * 16 + c;
                int bb = brow * 128 + ((ks * 64 + g * 16) ^ ((brow & 7) << 4));
                bfm[i] = *(const bf16x8*)((const char*)Bs + bb);
            }
            #pragma unroll
            for (int i = 0; i < 4; ++i)
                #pragma unroll
                for (int j = 0; j < 4; ++j)
                    acc[i][j] = MFMA16(af[i], bfm[j], acc[i][j]);
        }
    }

    if (which < 2) {
        __hip_bfloat16* Cq = which == 0 ? Qo : Ko;
        #pragma unroll
        for (int i = 0; i < 4; ++i)
            #pragma unroll
            for (int j = 0; j < 4; ++j)
                #pragma unroll
                for (int r = 0; r < 4; ++r) {
                    float v = acc[i][j][r];
                    float vp = __shfl_xor(v, 1);   // partner d^1 (c parity == d parity)
                    int m = m0 + wr * 64 + i * 16 + 4 * g + r;
                    int n = n0 + wc * 64 + j * 16 + c;
                    int srow = m & (S_ - 1), d = n & (DK_ - 1);
                    float cs = CT[srow * 64 + (d >> 1)];
                    float sn = ST[srow * 64 + (d >> 1)];
                    float o = (c & 1) ? __builtin_fmaf(v, cs, vp * sn)
                                      : __builtin_fmaf(v, cs, -vp * sn);
                    size_t a = ((size_t)((m >> 11) * 16 + (n >> 7)) * S_ + srow) * DK_ + d;
                    Cq[a] = __float2bfloat16(o);
                }
    } else {
        // V: write transposed (b,h,d,s); 4 consecutive s per lane -> packed 8B store
        #pragma unroll
        for (int i = 0; i < 4; ++i)
            #pragma unroll
            for (int j = 0; j < 4; ++j) {
                int m = m0 + wr * 64 + i * 16 + 4 * g;     // r=0 row
                int n = n0 + wc * 64 + j * 16 + c;
                int s0 = m & (S_ - 1), d = n & (DK_ - 1);
                __hip_bfloat16 ob[4];
                #pragma unroll
                for (int r = 0; r < 4; ++r) ob[r] = __float2bfloat16(acc[i][j][r]);
                ushort4 u; __builtin_memcpy(&u, ob, 8);
                size_t a = ((size_t)((m >> 11) * 16 + (n >> 7)) * DK_ + d) * S_ + s0;
                *(ushort4*)(Vo + a) = u;
            }
    }
}

// ---------------- out-projection GEMM (f32 out), 128x128 2-phase (NO setprio) -------
__global__ __launch_bounds__(256, 2)
void gemm_out(const __hip_bfloat16* __restrict__ A, const __hip_bfloat16* __restrict__ W,
              float* __restrict__ Cout, int M, int N, int K)
{
    __shared__ __align__(16) __hip_bfloat16 As[128 * 64];
    __shared__ __align__(16) __hip_bfloat16 Bs[128 * 64];
    const int tid = threadIdx.x;
    const int lane = tid & 63, wv = tid >> 6;
    const int wr = wv >> 1, wc = wv & 1;
    const int m0 = blockIdx.x * 128, n0 = blockIdx.y * 128;
    const int g = lane >> 4, c = lane & 15;

    f32x4 acc[4][4];
    #pragma unroll
    for (int i = 0; i < 4; ++i)
        #pragma unroll
        for (int j = 0; j < 4; ++j) acc[i][j] = f32x4{0.f, 0.f, 0.f, 0.f};

    for (int k0 = 0; k0 < K; k0 += 64) {
        __syncthreads();
        #pragma unroll
        for (int it = 0; it < 4; ++it) {
            int o = (it * 256 + tid) * 16;
            int row = o >> 7;
            int colb = (o ^ ((row & 7) << 4)) & 127;
            GLD16((const char*)(A + (size_t)(m0 + row) * K + k0) + colb, (char*)As + o);
            GLD16((const char*)(W + (size_t)(n0 + row) * K + k0) + colb, (char*)Bs + o);
        }
        __syncthreads();
        #pragma unroll
        for (int ks = 0; ks < 2; ++ks) {
            bf16x8 af[4], bfm[4];
            #pragma unroll
            for (int i = 0; i < 4; ++i) {
                int arow = wr * 64 + i * 16 + c;
                int ab = arow * 128 + ((ks * 64 + g * 16) ^ ((arow & 7) << 4));
                af[i] = *(const bf16x8*)((const char*)As + ab);
                int brow = wc * 64 + i * 16 + c;
                int bb = brow * 128 + ((ks * 64 + g * 16) ^ ((brow & 7) << 4));
                bfm[i] = *(const bf16x8*)((const char*)Bs + bb);
            }
            #pragma unroll
            for (int i = 0; i < 4; ++i)
                #pragma unroll
                for (int j = 0; j < 4; ++j)
                    acc[i][j] = MFMA16(af[i], bfm[j], acc[i][j]);
        }
    }

    #pragma unroll
    for (int i = 0; i < 4; ++i)
        #pragma unroll
        for (int j = 0; j < 4; ++j)
            #pragma unroll
            for (int r = 0; r < 4; ++r) {
                int m = m0 + wr * 64 + i * 16 + 4 * g + r;
                int n = n0 + wc * 64 + j * 16 + c;
                Cout[(size_t)m * N + n] = acc[i][j][r];
            }
}

// ---------------- flash attention (causal), XCD-pinned + balanced pairs ---------
// Round-11 attn kept verbatim: setprio (m191 attn-regime win) + P stride 76
// (conflict-free P writes) + deferred-L reduce + gated row-max reduce.
__device__ __forceinline__ void stage_kv(const __hip_bfloat16* Kp, const __hip_bfloat16* Vp,
                                         char* ks, char* vs, int kv0, int tid) {
    #pragma unroll
    for (int it = 0; it < 4; ++it) {
        int o = (it * 256 + tid) * 16;
        int row = o >> 8;
        int cb = (o ^ ((row & 7) << 4)) & 255;
        GLD16((const char*)(Kp + (size_t)(kv0 + row) * DK_) + cb, ks + o);
    }
    #pragma unroll
    for (int it = 0; it < 4; ++it) {
        int o = (it * 256 + tid) * 16;
        int row = o >> 7;
        int cb = (o ^ ((row & 7) << 4)) & 127;
        GLD16((const char*)(Vp + (size_t)row * S_ + kv0) + cb, vs + o);
    }
}

__global__ __launch_bounds__(256, 2)
void attn_kernel(const __hip_bfloat16* __restrict__ Q,
                 const __hip_bfloat16* __restrict__ Kt,
                 const __hip_bfloat16* __restrict__ VT,
                 __hip_bfloat16* __restrict__ O)
{
    __shared__ __align__(16) __hip_bfloat16 Ks[2][64 * 128];
    __shared__ __align__(16) __hip_bfloat16 Vs[2][128 * 64];
    __shared__ __align__(16) __hip_bfloat16 Ps[4][16 * PPAD_];

    const int tid = threadIdx.x, lane = tid & 63, w = tid >> 6;
    const int g = lane >> 4, c = lane & 15;
    const int id = blockIdx.x;
    const int slot = id & 7, jj = id >> 3;
    const int bh = ((jj >> 4) << 3) | slot;
    const int xq = jj & 15;
    const int b = bh >> 4, h = bh & 15;
    const size_t base_bh = (size_t)bh * S_ * DK_;
    const __hip_bfloat16* Qp = Q + base_bh;
    const __hip_bfloat16* Kp = Kt + base_bh;
    const __hip_bfloat16* Vp = VT + base_bh;

    #pragma unroll 1
    for (int pass = 0; pass < 2; ++pass) {
        const int qt = pass ? (31 - xq) : xq;
        const int qw = qt * 64 + w * 16;
        const int ntiles = qt + 1;

        bf16x8 qf[4];
        #pragma unroll
        for (int ds = 0; ds < 4; ++ds)
            qf[ds] = *(const bf16x8*)(Qp + (size_t)(qw + c) * DK_ + ds * 32 + g * 8);

        f32x4 oacc[8];
        #pragma unroll
        for (int fd = 0; fd < 8; ++fd) oacc[fd] = f32x4{0.f, 0.f, 0.f, 0.f};
        float M[4], Lp[4];
        #pragma unroll
        for (int r = 0; r < 4; ++r) { M[r] = -1e30f; Lp[r] = 0.f; }

        stage_kv(Kp, Vp, (char*)Ks[0], (char*)Vs[0], 0, tid);
        __syncthreads();

        int cur = 0;
        for (int t = 0; t < ntiles; ++t) {
            const int kv0 = t * 64;
            if (t + 1 < ntiles)
                stage_kv(Kp, Vp, (char*)Ks[cur ^ 1], (char*)Vs[cur ^ 1], kv0 + 64, tid);

            const bool diag = (kv0 + 63 > qw);

            f32x4 sacc[4];
            #pragma unroll
            for (int f = 0; f < 4; ++f) sacc[f] = f32x4{0.f, 0.f, 0.f, 0.f};
            __builtin_amdgcn_s_setprio(1);
            #pragma unroll
            for (int f = 0; f < 4; ++f) {
                #pragma unroll
                for (int ds = 0; ds < 4; ++ds) {
                    int krow = f * 16 + c;
                    int kbyt = krow * 256 + ((ds * 64 + g * 16) ^ ((krow & 7) << 4));
                    bf16x8 kf = *(const bf16x8*)((const char*)Ks[cur] + kbyt);
                    sacc[f] = MFMA16(qf[ds], kf, sacc[f]);
                }
            }
            __builtin_amdgcn_s_setprio(0);

            float p[4][4];
            float mt[4] = {-1e30f, -1e30f, -1e30f, -1e30f};
            #pragma unroll
            for (int f = 0; f < 4; ++f)
                #pragma unroll
                for (int r = 0; r < 4; ++r) {
                    float v = sacc[f][r];
                    if (diag && (kv0 + f * 16 + c > qw + 4 * g + r)) v = -1e30f;
                    p[f][r] = v;
                    mt[r] = fmaxf(mt[r], v);
                }
            // defer-max pre-check on LOCAL maxima (no reduce needed unless growing)
            bool grow = (mt[0] > M[0] + THR_RAW_) || (mt[1] > M[1] + THR_RAW_) ||
                        (mt[2] > M[2] + THR_RAW_) || (mt[3] > M[3] + THR_RAW_);
            if (__any(grow)) {
                float al[4];
                #pragma unroll
                for (int r = 0; r < 4; ++r) {   // full row-max reduce (rare path)
                    float v = mt[r];
                    v = fmaxf(v, __shfl_xor(v, 1));
                    v = fmaxf(v, __shfl_xor(v, 2));
                    v = fmaxf(v, __shfl_xor(v, 4));
                    v = fmaxf(v, __shfl_xor(v, 8));
                    float mn = fmaxf(M[r], v);
                    al[r] = __expf((M[r] - mn) * SCALE_);
                    M[r] = mn;
                    Lp[r] *= al[r];
                }
                #pragma unroll
                for (int fd = 0; fd < 8; ++fd)
                    #pragma unroll
                    for (int r = 0; r < 4; ++r) oacc[fd][r] *= al[r];
            }
            float ms[4];
            #pragma unroll
            for (int r = 0; r < 4; ++r) ms[r] = M[r] * SCALE_;
            #pragma unroll
            for (int f = 0; f < 4; ++f)
                #pragma unroll
                for (int r = 0; r < 4; ++r) {
                    float e = __expf(__builtin_fmaf(p[f][r], SCALE_, -ms[r]));
                    Lp[r] += e;                      // per-lane partial; reduce at end
                    Ps[w][(4 * g + r) * PPAD_ + f * 16 + c] = __float2bfloat16(e);
                }

            #pragma unroll
            for (int ks2 = 0; ks2 < 2; ++ks2) {
                bf16x8 pf = *(const bf16x8*)&Ps[w][c * PPAD_ + ks2 * 32 + g * 8];
                __builtin_amdgcn_s_setprio(1);
                #pragma unroll
                for (int fd = 0; fd < 8; ++fd) {
                    int vrow = fd * 16 + c;
                    int vb = vrow * 128 + ((ks2 * 64 + g * 16) ^ ((vrow & 7) << 4));
                    bf16x8 vf = *(const bf16x8*)((const char*)Vs[cur] + vb);
                    oacc[fd] = MFMA16(pf, vf, oacc[fd]);
                }
                __builtin_amdgcn_s_setprio(0);
            }
            __syncthreads();
            cur ^= 1;
        }

        float rl[4];
        #pragma unroll
        for (int r = 0; r < 4; ++r) {       // deferred L reduce (once per pass)
            float v = Lp[r];
            v += __shfl_xor(v, 1);
            v += __shfl_xor(v, 2);
            v += __shfl_xor(v, 4);
            v += __shfl_xor(v, 8);
            rl[r] = 1.0f / v;
        }
        #pragma unroll
        for (int fd = 0; fd < 8; ++fd) {
            #pragma unroll
            for (int r = 0; r < 4; ++r) {
                int s = qw + 4 * g + r;
                size_t a = ((size_t)(b * S_ + s)) * (H_ * DK_) + h * DK_ + fd * 16 + c;
                O[a] = __float2bfloat16(oacc[fd][r] * rl[r]);
            }
        }
    }
}

extern "C" void kernel_launch(void* const* d_in, const int* in_sizes, int n_in,
                              void* d_out, int out_size, void* d_ws, size_t ws_size,
                              hipStream_t stream) {
    const float* x  = (const float*)d_in[0];
    const float* wq = (const float*)d_in[1];
    const float* wk = (const float*)d_in[2];
    const float* wv = (const float*)d_in[3];
    const float* wo = (const float*)d_in[4];
    const float* pe = (const float*)d_in[5];
    float* out = (float*)d_out;

    const size_t XE = (size_t)B_ * S_ * E_;   // 8388608
    const size_t WE = (size_t)E_ * H_ * DK_;  // 4194304
    __hip_bfloat16* xb  = (__hip_bfloat16*)d_ws;
    __hip_bfloat16* wqb = xb + XE;
    __hip_bfloat16* wkb = wqb + WE;
    __hip_bfloat16* wvb = wkb + WE;
    __hip_bfloat16* wob = wvb + WE;
    __hip_bfloat16* qb  = wob + WE;  // (B,H,S,DK)
    __hip_bfloat16* kb  = qb + XE;   // (B,H,S,DK)
    __hip_bfloat16* vT  = kb + XE;   // (B,H,DK,S)
    __hip_bfloat16* at  = vT + XE;   // (B*S, H*DK)
    float* ct = (float*)(at + XE);
    float* st = ct + (size_t)S_ * 64;

    cast_all<<<dim3((int)(XE / 4 / 256), 5), 256, 0, stream>>>(
        x, wq, wk, wv, wo, xb, wqb, wkb, wvb, wob, (int)(XE / 4), (int)(WE / 4));
    trig_table<<<dim3(S_ * 64 / 256), 256, 0, stream>>>(pe, ct, st);

    gemm_qkv<<<dim3(32, 48), 256, 0, stream>>>(xb, wqb, wkb, wvb, qb, kb, vT, ct, st);

    attn_kernel<<<dim3(512), 256, 0, stream>>>(qb, kb, vT, at);

    gemm_out<<<dim3(32, 16), 256, 0, stream>>>(at, wob, out, B_ * S_, E_, H_ * DK_);
}

// Round 13
// 256.066 us; speedup vs baseline: 1.0099x; 1.0099x over previous
//
#include <hip/hip_runtime.h>
#include <hip/hip_bf16.h>

typedef __attribute__((ext_vector_type(8))) short bf16x8;
typedef __attribute__((ext_vector_type(4))) float f32x4;
typedef unsigned short u16;
typedef unsigned int u32;

#define B_ 2
#define S_ 2048
#define E_ 2048
#define H_ 16
#define DK_ 128
#define SCALE_ 0.08838834764831845f  // 1/sqrt(128)
#define THR_RAW_ 90.5f               // defer-max threshold: 8 / SCALE_
#define PPAD_ 76                     // P row stride: 38 dwords -> conflict-free P writes

#define MFMA16(a,b,c) __builtin_amdgcn_mfma_f32_16x16x32_bf16((a),(b),(c),0,0,0)
#define GLD16(g, l) __builtin_amdgcn_global_load_lds((const __attribute__((address_space(1))) void*)(g), (__attribute__((address_space(3))) void*)(l), 16, 0, 0)

__device__ __forceinline__ float b2f(short s) {
    u32 u = ((u32)(u16)s) << 16;
    float f; __builtin_memcpy(&f, &u, 4); return f;
}

// ---------------- casts: one launch, gridy 0..4 selects tensor ----------------
__global__ void cast_all(const float* __restrict__ x,
                         const float* __restrict__ w0, const float* __restrict__ w1,
                         const float* __restrict__ w2, const float* __restrict__ w3,
                         __hip_bfloat16* __restrict__ xo,
                         __hip_bfloat16* __restrict__ o0, __hip_bfloat16* __restrict__ o1,
                         __hip_bfloat16* __restrict__ o2, __hip_bfloat16* __restrict__ o3,
                         int nx4, int nw4) {
    int i = blockIdx.x * blockDim.x + threadIdx.x;
    const int y = blockIdx.y;
    const float* in; __hip_bfloat16* out; int n4;
    if (y == 0)      { in = x;  out = xo; n4 = nx4; }
    else if (y == 1) { in = w0; out = o0; n4 = nw4; }
    else if (y == 2) { in = w1; out = o1; n4 = nw4; }
    else if (y == 3) { in = w2; out = o2; n4 = nw4; }
    else             { in = w3; out = o3; n4 = nw4; }
    if (i >= n4) return;
    float4 v = ((const float4*)in)[i];
    __hip_bfloat16 ob[4] = {__float2bfloat16(v.x), __float2bfloat16(v.y),
                            __float2bfloat16(v.z), __float2bfloat16(v.w)};
    ushort4 u; __builtin_memcpy(&u, ob, 8);
    ((ushort4*)out)[i] = u;
}

// ---------------- trig table ----------------
__global__ void trig_table(const float* __restrict__ pe, float* __restrict__ ct,
                           float* __restrict__ st) {
    int t = blockIdx.x * blockDim.x + threadIdx.x;
    int s = t >> 6, d2 = t & 63;
    float ang = pe[(size_t)s * DK_ + 2 * d2];
    ct[t] = cosf(ang);
    st[t] = sinf(ang);
}

// ---------------- fused QKV projection GEMM + RoPE epilogue (round-3 exact) ----------
// grid (32, 48): which = blockIdx.y/16 selects {wq,wk,wv}; ntile = blockIdx.y%16.
// Dispatch order x-fast keeps the X working set per XCD small (FETCH ~120MB, 107us).
__global__ __launch_bounds__(256, 2)
void gemm_qkv(const __hip_bfloat16* __restrict__ X,
              const __hip_bfloat16* __restrict__ WQ, const __hip_bfloat16* __restrict__ WK,
              const __hip_bfloat16* __restrict__ WV,
              __hip_bfloat16* __restrict__ Qo, __hip_bfloat16* __restrict__ Ko,
              __hip_bfloat16* __restrict__ Vo,
              const float* __restrict__ CT, const float* __restrict__ ST)
{
    __shared__ __align__(16) __hip_bfloat16 As[128 * 64];
    __shared__ __align__(16) __hip_bfloat16 Bs[128 * 64];
    const int tid = threadIdx.x;
    const int lane = tid & 63, wv = tid >> 6;
    const int wr = wv >> 1, wc = wv & 1;
    const int which = blockIdx.y >> 4;
    const __hip_bfloat16* W = which == 0 ? WQ : which == 1 ? WK : WV;
    const int m0 = blockIdx.x * 128, n0 = (blockIdx.y & 15) * 128;
    const int g = lane >> 4, c = lane & 15;
    const int K = E_;

    f32x4 acc[4][4];
    #pragma unroll
    for (int i = 0; i < 4; ++i)
        #pragma unroll
        for (int j = 0; j < 4; ++j) acc[i][j] = f32x4{0.f, 0.f, 0.f, 0.f};

    for (int k0 = 0; k0 < K; k0 += 64) {
        __syncthreads();
        #pragma unroll
        for (int it = 0; it < 4; ++it) {
            int o = (it * 256 + tid) * 16;
            int row = o >> 7;
            int colb = (o ^ ((row & 7) << 4)) & 127;
            GLD16((const char*)(X + (size_t)(m0 + row) * K + k0) + colb, (char*)As + o);
            GLD16((const char*)(W + (size_t)(n0 + row) * K + k0) + colb, (char*)Bs + o);
        }
        __syncthreads();
        #pragma unroll
        for (int ks = 0; ks < 2; ++ks) {
            bf16x8 af[4], bfm[4];
            #pragma unroll
            for (int i = 0; i < 4; ++i) {
                int arow = wr * 64 + i * 16 + c;
                int ab = arow * 128 + ((ks * 64 + g * 16) ^ ((arow & 7) << 4));
                af[i] = *(const bf16x8*)((const char*)As + ab);
                int brow = wc * 64 + i * 16 + c;
                int bb = brow * 128 + ((ks * 64 + g * 16) ^ ((brow & 7) << 4));
                bfm[i] = *(const bf16x8*)((const char*)Bs + bb);
            }
            #pragma unroll
            for (int i = 0; i < 4; ++i)
                #pragma unroll
                for (int j = 0; j < 4; ++j)
                    acc[i][j] = MFMA16(af[i], bfm[j], acc[i][j]);
        }
    }

    if (which < 2) {
        __hip_bfloat16* Cq = which == 0 ? Qo : Ko;
        #pragma unroll
        for (int i = 0; i < 4; ++i)
            #pragma unroll
            for (int j = 0; j < 4; ++j)
                #pragma unroll
                for (int r = 0; r < 4; ++r) {
                    float v = acc[i][j][r];
                    float vp = __shfl_xor(v, 1);   // partner d^1 (c parity == d parity)
                    int m = m0 + wr * 64 + i * 16 + 4 * g + r;
                    int n = n0 + wc * 64 + j * 16 + c;
                    int srow = m & (S_ - 1), d = n & (DK_ - 1);
                    float cs = CT[srow * 64 + (d >> 1)];
                    float sn = ST[srow * 64 + (d >> 1)];
                    float o = (c & 1) ? __builtin_fmaf(v, cs, vp * sn)
                                      : __builtin_fmaf(v, cs, -vp * sn);
                    size_t a = ((size_t)((m >> 11) * 16 + (n >> 7)) * S_ + srow) * DK_ + d;
                    Cq[a] = __float2bfloat16(o);
                }
    } else {
        // V: write transposed (b,h,d,s); 4 consecutive s per lane -> packed 8B store
        #pragma unroll
        for (int i = 0; i < 4; ++i)
            #pragma unroll
            for (int j = 0; j < 4; ++j) {
                int m = m0 + wr * 64 + i * 16 + 4 * g;     // r=0 row
                int n = n0 + wc * 64 + j * 16 + c;
                int s0 = m & (S_ - 1), d = n & (DK_ - 1);
                __hip_bfloat16 ob[4];
                #pragma unroll
                for (int r = 0; r < 4; ++r) ob[r] = __float2bfloat16(acc[i][j][r]);
                ushort4 u; __builtin_memcpy(&u, ob, 8);
                size_t a = ((size_t)((m >> 11) * 16 + (n >> 7)) * DK_ + d) * S_ + s0;
                *(ushort4*)(Vo + a) = u;
            }
    }
}

// ---------------- out-projection GEMM (f32 out), 128x128 2-phase ----------------
__global__ __launch_bounds__(256, 2)
void gemm_out(const __hip_bfloat16* __restrict__ A, const __hip_bfloat16* __restrict__ W,
              float* __restrict__ Cout, int M, int N, int K)
{
    __shared__ __align__(16) __hip_bfloat16 As[128 * 64];
    __shared__ __align__(16) __hip_bfloat16 Bs[128 * 64];
    const int tid = threadIdx.x;
    const int lane = tid & 63, wv = tid >> 6;
    const int wr = wv >> 1, wc = wv & 1;
    const int m0 = blockIdx.x * 128, n0 = blockIdx.y * 128;
    const int g = lane >> 4, c = lane & 15;

    f32x4 acc[4][4];
    #pragma unroll
    for (int i = 0; i < 4; ++i)
        #pragma unroll
        for (int j = 0; j < 4; ++j) acc[i][j] = f32x4{0.f, 0.f, 0.f, 0.f};

    for (int k0 = 0; k0 < K; k0 += 64) {
        __syncthreads();
        #pragma unroll
        for (int it = 0; it < 4; ++it) {
            int o = (it * 256 + tid) * 16;
            int row = o >> 7;
            int colb = (o ^ ((row & 7) << 4)) & 127;
            GLD16((const char*)(A + (size_t)(m0 + row) * K + k0) + colb, (char*)As + o);
            GLD16((const char*)(W + (size_t)(n0 + row) * K + k0) + colb, (char*)Bs + o);
        }
        __syncthreads();
        #pragma unroll
        for (int ks = 0; ks < 2; ++ks) {
            bf16x8 af[4], bfm[4];
            #pragma unroll
            for (int i = 0; i < 4; ++i) {
                int arow = wr * 64 + i * 16 + c;
                int ab = arow * 128 + ((ks * 64 + g * 16) ^ ((arow & 7) << 4));
                af[i] = *(const bf16x8*)((const char*)As + ab);
                int brow = wc * 64 + i * 16 + c;
                int bb = brow * 128 + ((ks * 64 + g * 16) ^ ((brow & 7) << 4));
                bfm[i] = *(const bf16x8*)((const char*)Bs + bb);
            }
            #pragma unroll
            for (int i = 0; i < 4; ++i)
                #pragma unroll
                for (int j = 0; j < 4; ++j)
                    acc[i][j] = MFMA16(af[i], bfm[j], acc[i][j]);
        }
    }

    #pragma unroll
    for (int i = 0; i < 4; ++i)
        #pragma unroll
        for (int j = 0; j < 4; ++j)
            #pragma unroll
            for (int r = 0; r < 4; ++r) {
                int m = m0 + wr * 64 + i * 16 + 4 * g + r;
                int n = n0 + wc * 64 + j * 16 + c;
                Cout[(size_t)m * N + n] = acc[i][j][r];
            }
}

// ---------------- flash attention (causal), 3 blocks/CU single-buffer variant ---------
// LDS 74KB->41KB (single K/V buffer) => 3 blocks/CU, 12 waves/CU (was 2, 8). The lost
// intra-block stage/compute overlap is covered by inter-block overlap (r1->r2 gradient:
// occupancy 11->21% gave 176->103us; this pushes 21->31%). K/V stages are XCD-pinned
// L2 hits (~200-300cy exposed per tile, hidden by 2 other resident blocks).
__device__ __forceinline__ void stage_kv(const __hip_bfloat16* Kp, const __hip_bfloat16* Vp,
                                         char* ks, char* vs, int kv0, int tid) {
    #pragma unroll
    for (int it = 0; it < 4; ++it) {
        int o = (it * 256 + tid) * 16;
        int row = o >> 8;
        int cb = (o ^ ((row & 7) << 4)) & 255;
        GLD16((const char*)(Kp + (size_t)(kv0 + row) * DK_) + cb, ks + o);
    }
    #pragma unroll
    for (int it = 0; it < 4; ++it) {
        int o = (it * 256 + tid) * 16;
        int row = o >> 7;
        int cb = (o ^ ((row & 7) << 4)) & 127;
        GLD16((const char*)(Vp + (size_t)row * S_ + kv0) + cb, vs + o);
    }
}

__global__ __launch_bounds__(256, 3)
void attn_kernel(const __hip_bfloat16* __restrict__ Q,
                 const __hip_bfloat16* __restrict__ Kt,
                 const __hip_bfloat16* __restrict__ VT,
                 __hip_bfloat16* __restrict__ O)
{
    __shared__ __align__(16) __hip_bfloat16 Ks[64 * 128];
    __shared__ __align__(16) __hip_bfloat16 Vs[128 * 64];
    __shared__ __align__(16) __hip_bfloat16 Ps[4][16 * PPAD_];

    const int tid = threadIdx.x, lane = tid & 63, w = tid >> 6;
    const int g = lane >> 4, c = lane & 15;
    const int id = blockIdx.x;
    const int slot = id & 7, jj = id >> 3;
    const int bh = ((jj >> 4) << 3) | slot;
    const int xq = jj & 15;
    const int b = bh >> 4, h = bh & 15;
    const size_t base_bh = (size_t)bh * S_ * DK_;
    const __hip_bfloat16* Qp = Q + base_bh;
    const __hip_bfloat16* Kp = Kt + base_bh;
    const __hip_bfloat16* Vp = VT + base_bh;

    #pragma unroll 1
    for (int pass = 0; pass < 2; ++pass) {
        const int qt = pass ? (31 - xq) : xq;
        const int qw = qt * 64 + w * 16;
        const int ntiles = qt + 1;

        bf16x8 qf[4];
        #pragma unroll
        for (int ds = 0; ds < 4; ++ds)
            qf[ds] = *(const bf16x8*)(Qp + (size_t)(qw + c) * DK_ + ds * 32 + g * 8);

        f32x4 oacc[8];
        #pragma unroll
        for (int fd = 0; fd < 8; ++fd) oacc[fd] = f32x4{0.f, 0.f, 0.f, 0.f};
        float M[4], Lp[4];
        #pragma unroll
        for (int r = 0; r < 4; ++r) { M[r] = -1e30f; Lp[r] = 0.f; }

        for (int t = 0; t < ntiles; ++t) {
            const int kv0 = t * 64;
            stage_kv(Kp, Vp, (char*)Ks, (char*)Vs, kv0, tid);
            __syncthreads();          // drain stage (vmcnt 0) + all waves see K/V

            const bool diag = (kv0 + 63 > qw);

            f32x4 sacc[4];
            #pragma unroll
            for (int f = 0; f < 4; ++f) sacc[f] = f32x4{0.f, 0.f, 0.f, 0.f};
            __builtin_amdgcn_s_setprio(1);
            #pragma unroll
            for (int f = 0; f < 4; ++f) {
                #pragma unroll
                for (int ds = 0; ds < 4; ++ds) {
                    int krow = f * 16 + c;
                    int kbyt = krow * 256 + ((ds * 64 + g * 16) ^ ((krow & 7) << 4));
                    bf16x8 kf = *(const bf16x8*)((const char*)Ks + kbyt);
                    sacc[f] = MFMA16(qf[ds], kf, sacc[f]);
                }
            }
            __builtin_amdgcn_s_setprio(0);

            float p[4][4];
            float mt[4] = {-1e30f, -1e30f, -1e30f, -1e30f};
            #pragma unroll
            for (int f = 0; f < 4; ++f)
                #pragma unroll
                for (int r = 0; r < 4; ++r) {
                    float v = sacc[f][r];
                    if (diag && (kv0 + f * 16 + c > qw + 4 * g + r)) v = -1e30f;
                    p[f][r] = v;
                    mt[r] = fmaxf(mt[r], v);
                }
            // defer-max pre-check on LOCAL maxima (no reduce needed unless growing)
            bool grow = (mt[0] > M[0] + THR_RAW_) || (mt[1] > M[1] + THR_RAW_) ||
                        (mt[2] > M[2] + THR_RAW_) || (mt[3] > M[3] + THR_RAW_);
            if (__any(grow)) {
                float al[4];
                #pragma unroll
                for (int r = 0; r < 4; ++r) {   // full row-max reduce (rare path)
                    float v = mt[r];
                    v = fmaxf(v, __shfl_xor(v, 1));
                    v = fmaxf(v, __shfl_xor(v, 2));
                    v = fmaxf(v, __shfl_xor(v, 4));
                    v = fmaxf(v, __shfl_xor(v, 8));
                    float mn = fmaxf(M[r], v);
                    al[r] = __expf((M[r] - mn) * SCALE_);
                    M[r] = mn;
                    Lp[r] *= al[r];
                }
                #pragma unroll
                for (int fd = 0; fd < 8; ++fd)
                    #pragma unroll
                    for (int r = 0; r < 4; ++r) oacc[fd][r] *= al[r];
            }
            float ms[4];
            #pragma unroll
            for (int r = 0; r < 4; ++r) ms[r] = M[r] * SCALE_;
            #pragma unroll
            for (int f = 0; f < 4; ++f)
                #pragma unroll
                for (int r = 0; r < 4; ++r) {
                    float e = __expf(__builtin_fmaf(p[f][r], SCALE_, -ms[r]));
                    Lp[r] += e;                      // per-lane partial; reduce at end
                    Ps[w][(4 * g + r) * PPAD_ + f * 16 + c] = __float2bfloat16(e);
                }

            #pragma unroll
            for (int ks2 = 0; ks2 < 2; ++ks2) {
                bf16x8 pf = *(const bf16x8*)&Ps[w][c * PPAD_ + ks2 * 32 + g * 8];
                __builtin_amdgcn_s_setprio(1);
                #pragma unroll
                for (int fd = 0; fd < 8; ++fd) {
                    int vrow = fd * 16 + c;
                    int vb = vrow * 128 + ((ks2 * 64 + g * 16) ^ ((vrow & 7) << 4));
                    bf16x8 vf = *(const bf16x8*)((const char*)Vs + vb);
                    oacc[fd] = MFMA16(pf, vf, oacc[fd]);
                }
                __builtin_amdgcn_s_setprio(0);
            }
            __syncthreads();          // all waves done reading before next stage overwrites
        }

        float rl[4];
        #pragma unroll
        for (int r = 0; r < 4; ++r) {       // deferred L reduce (once per pass)
            float v = Lp[r];
            v += __shfl_xor(v, 1);
            v += __shfl_xor(v, 2);
            v += __shfl_xor(v, 4);
            v += __shfl_xor(v, 8);
            rl[r] = 1.0f / v;
        }
        #pragma unroll
        for (int fd = 0; fd < 8; ++fd) {
            #pragma unroll
            for (int r = 0; r < 4; ++r) {
                int s = qw + 4 * g + r;
                size_t a = ((size_t)(b * S_ + s)) * (H_ * DK_) + h * DK_ + fd * 16 + c;
                O[a] = __float2bfloat16(oacc[fd][r] * rl[r]);
            }
        }
    }
}

extern "C" void kernel_launch(void* const* d_in, const int* in_sizes, int n_in,
                              void* d_out, int out_size, void* d_ws, size_t ws_size,
                              hipStream_t stream) {
    const float* x  = (const float*)d_in[0];
    const float* wq = (const float*)d_in[1];
    const float* wk = (const float*)d_in[2];
    const float* wv = (const float*)d_in[3];
    const float* wo = (const float*)d_in[4];
    const float* pe = (const float*)d_in[5];
    float* out = (float*)d_out;

    const size_t XE = (size_t)B_ * S_ * E_;   // 8388608
    const size_t WE = (size_t)E_ * H_ * DK_;  // 4194304
    __hip_bfloat16* xb  = (__hip_bfloat16*)d_ws;
    __hip_bfloat16* wqb = xb + XE;
    __hip_bfloat16* wkb = wqb + WE;
    __hip_bfloat16* wvb = wkb + WE;
    __hip_bfloat16* wob = wvb + WE;
    __hip_bfloat16* qb  = wob + WE;  // (B,H,S,DK)
    __hip_bfloat16* kb  = qb + XE;   // (B,H,S,DK)
    __hip_bfloat16* vT  = kb + XE;   // (B,H,DK,S)
    __hip_bfloat16* at  = vT + XE;   // (B*S, H*DK)
    float* ct = (float*)(at + XE);
    float* st = ct + (size_t)S_ * 64;

    cast_all<<<dim3((int)(XE / 4 / 256), 5), 256, 0, stream>>>(
        x, wq, wk, wv, wo, xb, wqb, wkb, wvb, wob, (int)(XE / 4), (int)(WE / 4));
    trig_table<<<dim3(S_ * 64 / 256), 256, 0, stream>>>(pe, ct, st);

    gemm_qkv<<<dim3(32, 48), 256, 0, stream>>>(xb, wqb, wkb, wvb, qb, kb, vT, ct, st);

    attn_kernel<<<dim3(512), 256, 0, stream>>>(qb, kb, vT, at);

    gemm_out<<<dim3(32, 16), 256, 0, stream>>>(at, wob, out, B_ * S_, E_, H_ * DK_);
}